// Round 12
// baseline (278.812 us; speedup 1.0000x reference)
//
#include <hip/hip_runtime.h>
#include <cstdint>
#include <cstddef>

// ---------------- problem constants (fixed by setup_inputs; k==32 always) ----
constexpr int B_SZ  = 256;
constexpr int T_SZ  = 8;
constexpr int DIN   = 768;
constexpr int DSAE  = 8192;
constexpr int KSEL  = 32;
constexpr int NROWS = B_SZ * T_SZ;        // 2048 (row r = b*T + t)
constexpr int CAND_CAP = 64;
constexpr int RCAP  = 32;                 // boundary-window capacity
constexpr float EPS_W = 3.2e-4f;          // conservative (~8 sigma, rne-A + rne-B)
constexpr int NSK   = DIN / 32;           // 24 K-steps

// ---------------- workspace layout (units: 4-byte words) ---------------------
constexpr size_t XC_SZ    = (size_t)NROWS * DIN;            // 1,572,864 w (6 MB)
constexpr size_t OFF_XC   = 0;
constexpr size_t OFF_XCP  = OFF_XC + XC_SZ;                 // packed bf16 xc
constexpr size_t XCP_W    = XC_SZ / 2;                      // 786,432 w (3 MB)
constexpr size_t OFF_SIDX = OFF_XCP + XCP_W;
constexpr size_t OFF_SVAL = OFF_SIDX + (size_t)NROWS * KSEL;
constexpr size_t OFF_BIG  = OFF_SVAL + (size_t)NROWS * KSEL;
constexpr size_t BIG_W    = (size_t)T_SZ * DSAE * DIN / 2;  // 25,165,824 w (100.6 MB)
constexpr size_t WS_FAST_WORDS = OFF_BIG + BIG_W;           // ~110 MB

typedef short bf16x8 __attribute__((ext_vector_type(8)));  // 8 bf16 = 4 VGPR
typedef float f32x4  __attribute__((ext_vector_type(4)));

// RNE fp32 -> bf16 (16-bit result in low bits)
__device__ inline unsigned rne1(float x) {
  unsigned u = __float_as_uint(x);
  return (u + 0x7FFFu + ((u >> 16) & 1u)) >> 16;
}
__device__ inline float bf16tof(unsigned short v) {
  return __uint_as_float((unsigned)v << 16);
}

// ---------------- tiny init --------------------------------------------------
__global__ void k_zero(float* p) { *p = 0.f; }

// ---------------- xc = x - b_dec ; also emit FRAGMENT-PACKED bf16 copy -------
// Packed-A layout (bytes): unit (gm,t,s) of 1 KB at ((gm*8+t)*24+s)*1024,
// lane l's 16 B at +l*16 holding rows b=gm*16+(l&15), k=s*32+(l>>4)*8 ..+8.
__global__ __launch_bounds__(256) void k_xc(const float* __restrict__ x,
                                            const float* __restrict__ bdec,
                                            float* __restrict__ xc,
                                            unsigned short* __restrict__ xcp) {
  const int c = blockIdx.x * 256 + threadIdx.x;   // 0 .. 196607
  const int lane = c & 63;
  const int u = c >> 6;
  const int s  = u % NSK;
  const int tt = (u / NSK) & (T_SZ - 1);
  const int gm = u / (NSK * T_SZ);                // 0..15
  const int b  = gm * 16 + (lane & 15);
  const int k0 = s * 32 + (lane >> 4) * 8;
  const size_t rowOff = ((size_t)(b * T_SZ + tt)) * DIN + k0;
  float4 v0 = *(const float4*)(x + rowOff);
  float4 v1 = *(const float4*)(x + rowOff + 4);
  float4 d0 = *(const float4*)(bdec + tt * DIN + k0);
  float4 d1 = *(const float4*)(bdec + tt * DIN + k0 + 4);
  v0.x -= d0.x; v0.y -= d0.y; v0.z -= d0.z; v0.w -= d0.w;
  v1.x -= d1.x; v1.y -= d1.y; v1.z -= d1.z; v1.w -= d1.w;
  *(float4*)(xc + rowOff) = v0;
  *(float4*)(xc + rowOff + 4) = v1;
  uint4 p;
  p.x = rne1(v0.x) | (rne1(v0.y) << 16);
  p.y = rne1(v0.z) | (rne1(v0.w) << 16);
  p.z = rne1(v1.x) | (rne1(v1.y) << 16);
  p.w = rne1(v1.z) | (rne1(v1.w) << 16);
  *(uint4*)(xcp + (size_t)c * 8) = p;
}

// ---------------- encoder: pre = xc @ W_enc[t]^T + b_enc (bf16 MFMA) ---------
// DRAM-page-locality fix: a 32-col x full-K Wenc tile is ONE CONTIGUOUS 96 KB
// region -> stage it with perfectly linear float4 streams (the 7 TB/s pattern),
// rne->bf16 into a 48 KB XOR-swizzled LDS tile, then 24 MFMA steps with
// single-ds_read_b128 B-frags. All prior k-slice encoders read 128 B per
// 3 KB-strided row -> DRAM row-buffer thrash capped them at 1.8 TB/s.
// 48 KB LDS -> 3 blocks/CU: one block's stage overlaps others' compute (TLP).
// A-frags from fragment-packed xcp (3 MB, L2-resident, 1 KB linear loads).
// Grid 256x8 = 2048 blocks, 256 thr (4 waves; wave = 64 x-rows x 32 cols).
__global__ __launch_bounds__(256, 3) void k_encoder(const unsigned short* __restrict__ xcp,
                                                    const float* __restrict__ Wenc,
                                                    const float* __restrict__ benc,
                                                    float* __restrict__ pre) {
  __shared__ __align__(16) short Bs[32 * DIN];   // 48 KB bf16, XOR-swizzled
  char* bsb = (char*)&Bs[0];
  const int t  = blockIdx.y;
  const int n0 = blockIdx.x * 32;
  const int tid = threadIdx.x;
  const int wm = tid >> 6, lane = tid & 63;
  const int l15 = lane & 15, kc = lane >> 4;

  // ---- stage: 24576 contiguous floats = rows n0..n0+32 of W_enc[t] --------
  const float* src = Wenc + ((size_t)t * DSAE + n0) * DIN;
#pragma unroll
  for (int b = 0; b < 2; ++b) {
    float4 v[12];
#pragma unroll
    for (int j = 0; j < 6; ++j) {                 // 8 KB contiguous per j
      const float* p = src + b * 12288 + j * 2048 + tid * 8;
      v[j * 2]     = *(const float4*)p;
      v[j * 2 + 1] = *(const float4*)(p + 4);
    }
#pragma unroll
    for (int j = 0; j < 6; ++j) {
      const int F   = b * 12288 + j * 2048 + tid * 8;   // tile float idx
      const int row = (((F >> 8) * 21846) >> 16);       // F / 768 (exact, F<24576)
      const int k   = F - row * DIN;
      const int addr = ((row * DIN + k) * 2) ^ ((row & 7) << 4);
      uint4 pkt;
      pkt.x = rne1(v[j*2].x)   | (rne1(v[j*2].y)   << 16);
      pkt.y = rne1(v[j*2].z)   | (rne1(v[j*2].w)   << 16);
      pkt.z = rne1(v[j*2+1].x) | (rne1(v[j*2+1].y) << 16);
      pkt.w = rne1(v[j*2+1].z) | (rne1(v[j*2+1].w) << 16);
      *(uint4*)(bsb + addr) = pkt;
    }
  }
  __syncthreads();

  // ---- compute: 24 K-steps; A packed-linear (1 KB/load), B one b128/frag ---
  const unsigned short* aB0 =
      xcp + ((size_t)(wm * 4 * T_SZ + t) * NSK) * 512 + lane * 8;
  constexpr size_t A_MI = (size_t)T_SZ * NSK * 512;   // +16 x-rows (halfwords)

  f32x4 acc[4][2] = {};
#pragma unroll 4
  for (int s = 0; s < NSK; ++s) {
    bf16x8 a[4], bfr[2];
#pragma unroll
    for (int mi = 0; mi < 4; ++mi)
      a[mi] = *(const bf16x8*)(aB0 + (size_t)s * 512 + mi * A_MI);
#pragma unroll
    for (int ni = 0; ni < 2; ++ni) {
      const int row = ni * 16 + l15;
      const int addr = ((row * DIN + s * 32 + kc * 8) * 2) ^ ((l15 & 7) << 4);
      bfr[ni] = *(const bf16x8*)(bsb + addr);
    }
#pragma unroll
    for (int mi = 0; mi < 4; ++mi)
#pragma unroll
      for (int ni = 0; ni < 2; ++ni)
        acc[mi][ni] = __builtin_amdgcn_mfma_f32_16x16x32_bf16(
            a[mi], bfr[ni], acc[mi][ni], 0, 0, 0);
  }

  // epilogue: C/D layout col=lane&15, row=(lane>>4)*4+reg
#pragma unroll
  for (int ni = 0; ni < 2; ++ni) {
    const int col = n0 + ni * 16 + l15;
    const float bias = benc[(size_t)t * DSAE + col];
#pragma unroll
    for (int mi = 0; mi < 4; ++mi) {
      const int rbase = wm * 64 + mi * 16 + kc * 4;
#pragma unroll
      for (int j = 0; j < 4; ++j)
        pre[((size_t)(rbase + j) * T_SZ + t) * DSAE + col] = acc[mi][ni][j] + bias;
    }
  }
}

// ---------------- fused top-k select -----------------------------------------
__global__ __launch_bounds__(256) void k_select(const float* __restrict__ xc,
                                                const float* __restrict__ Wenc,
                                                const float* __restrict__ benc,
                                                float* u,   // pre in, u out (aliased)
                                                int* __restrict__ sel_idx,
                                                float* __restrict__ sel_val) {
  const int r = blockIdx.x, t = r & (T_SZ - 1);
  __shared__ float sp[DSAE];     // 32 KB
  __shared__ float redf[4], redf2[4];
  __shared__ int   redi[4];
  __shared__ float cv[CAND_CAP]; __shared__ int ci[CAND_CAP];
  __shared__ float sv[CAND_CAP]; __shared__ int si[CAND_CAP];
  __shared__ float rv[RCAP];     __shared__ int ri[RCAP];
  __shared__ double rd[RCAP];
  __shared__ double xd[DIN];     // 6 KB
  __shared__ int   s_n, s_nR, s_A, s_nW;
  const int tid = threadIdx.x, lane = tid & 63, w = tid >> 6;
  float* urow = u + (size_t)r * DSAE;

  // load row + moments
  float s1 = 0.f, s2 = 0.f;
  for (int sgm = 0; sgm < DSAE / 256; ++sgm) {
    float v = urow[tid + sgm * 256];
    sp[tid + sgm * 256] = v;
    s1 += v; s2 = fmaf(v, v, s2);
  }
  for (int off = 32; off; off >>= 1) {
    s1 += __shfl_down(s1, off); s2 += __shfl_down(s2, off);
  }
  if (lane == 0) { redf[w] = s1; redf2[w] = s2; }
  __syncthreads();
  const float mean = (redf[0] + redf[1] + redf[2] + redf[3]) * (1.f / DSAE);
  const float var  = (redf2[0] + redf2[1] + redf2[2] + redf2[3]) * (1.f / DSAE) - mean * mean;
  const float sd   = sqrtf(fmaxf(var, 1e-20f));

  auto countGE = [&](float th) -> int {
    int c = 0;
#pragma unroll
    for (int sgm = 0; sgm < DSAE / 256; ++sgm)
      c += (sp[tid + sgm * 256] >= th) ? 1 : 0;
    for (int off = 32; off; off >>= 1) c += __shfl_down(c, off);
    __syncthreads();               // protect redi reuse
    if (lane == 0) redi[w] = c;
    __syncthreads();
    return redi[0] + redi[1] + redi[2] + redi[3];
  };

  float tlo = mean + 2.0f * sd, thi = mean + 3.5f * sd;
  for (int it = 0; it < 8 && countGE(tlo) < KSEL; ++it) tlo -= sd;
  float th = mean + 2.52f * sd;    // Gaussian seed: tail ~48/8192
  int c = countGE(th);
  for (int it = 0; it < 24 && (c < KSEL || c > CAND_CAP); ++it) {
    if (c > CAND_CAP) tlo = th; else thi = th;
    th = 0.5f * (tlo + thi);
    c = countGE(th);
  }
  if (c < KSEL) { th = tlo; c = countGE(th); }   // tlo has count >= 32

  // collect candidates >= th
  if (tid == 0) s_n = 0;
  __syncthreads();
  for (int sgm = 0; sgm < DSAE / 256; ++sgm) {
    int i = tid + sgm * 256;
    float v = sp[i];
    if (v >= th) {
      int p = atomicAdd(&s_n, 1);
      if (p < CAND_CAP) { cv[p] = v; ci[p] = i; }
    }
  }
  __syncthreads();
  const int n = s_n < CAND_CAP ? s_n : CAND_CAP;

  // sort desc (rank by value; ties lower idx first)
  if (tid < n) {
    float v = cv[tid]; int id = ci[tid];
    int rk = 0;
    for (int j = 0; j < n; ++j) {
      float vj = cv[j];
      rk += (vj > v || (vj == v && ci[j] < id)) ? 1 : 0;
    }
    sv[rk] = v; si[rk] = id;
  }
  __syncthreads();

  const float v32 = sv[KSEL - 1];
  const float wlo = v32 - EPS_W, whi = v32 + EPS_W;
  if (tid == 0) {
    int A = 0;
    while (A < KSEL - 1 && sv[A] > whi) ++A;       // certainly-selected count
    s_A = A;
    int e = A;
    while (e < n && sv[e] >= wlo) ++e;             // window members in collection
    s_nW = e - A;
  }
  __syncthreads();
  const int A  = s_A;
  const int nW = s_nW < RCAP ? s_nW : RCAP;
  if (tid < nW) { rv[tid] = sv[A + tid]; ri[tid] = si[A + tid]; }
  if (tid == 0) s_nR = nW;
  __syncthreads();
  // append window members below collection threshold (rare)
  if (th > wlo) {
    for (int sgm = 0; sgm < DSAE / 256; ++sgm) {
      int i = tid + sgm * 256;
      float v = sp[i];
      if (v >= wlo && v < th) {
        int p = atomicAdd(&s_nR, 1);
        if (p < RCAP) { rv[p] = v; ri[p] = i; }
      }
    }
  }
  __syncthreads();
  const int nR = s_nR < RCAP ? s_nR : RCAP;

  // fp64 refinement of boundary members (membership order + exact values)
  if (nR >= 2) {
    for (int i = tid; i < DIN; i += 256) xd[i] = (double)xc[(size_t)r * DIN + i];
    __syncthreads();
    for (int j = w; j < nR; j += 4) {   // one wave per member
      const int h = ri[j];
      const float* wrow = Wenc + ((size_t)t * DSAE + h) * DIN;
      double s = 0.0;
#pragma unroll
      for (int ss = 0; ss < DIN / 64; ++ss)
        s += xd[lane + 64 * ss] * (double)wrow[lane + 64 * ss];
      for (int off = 32; off; off >>= 1) s += __shfl_down(s, off);
      if (lane == 0) rd[j] = s + (double)benc[(size_t)t * DSAE + h];
    }
  } else if (nR == 1) {
    if (tid == 0) rd[0] = (double)rv[0];   // membership certain; pre value fine
  }
  __syncthreads();

  // overwrite row with u = zeros + scattered relu values
  for (int sgm = 0; sgm < DSAE / 256; ++sgm) urow[tid + sgm * 256] = 0.f;
  __syncthreads();

  if (tid < A) {   // A-set: pre values (err ~3e-5, far under threshold)
    float val = fmaxf(sv[tid], 0.f);
    urow[si[tid]] = val;
    sel_idx[(size_t)r * KSEL + tid] = si[tid];
    sel_val[(size_t)r * KSEL + tid] = val;
  }
  const int need = KSEL - A;
  if (tid < nR) {  // R-set: top-(32-A) by fp64 (ties lower idx)
    double v = rd[tid]; int id = ri[tid];
    int rk = 0;
    for (int j = 0; j < nR; ++j) {
      double vj = rd[j];
      rk += (vj > v || (vj == v && ri[j] < id)) ? 1 : 0;
    }
    if (rk < need) {
      float val = fmaxf((float)v, 0.f);
      urow[id] = val;
      sel_idx[(size_t)r * KSEL + A + rk] = id;
      sel_val[(size_t)r * KSEL + A + rk] = val;
    }
  }
}

// ---------------- W_dec transpose: (T,DIN,DSAE) f32 -> (T,DSAE,DIN) bf16 -----
__global__ __launch_bounds__(256) void k_transpose(const float* __restrict__ W,
                                                   unsigned short* __restrict__ Wt) {
  __shared__ float s[32][33];
  const int t  = blockIdx.z;
  const int h0 = blockIdx.x * 32;
  const int d0 = blockIdx.y * 32;
  const int c  = threadIdx.x & 31, rr = threadIdx.x >> 5;  // 8 rows/pass
#pragma unroll
  for (int q = 0; q < 4; ++q) {
    int d = d0 + rr + q * 8;
    s[rr + q * 8][c] = W[((size_t)t * DIN + d) * DSAE + h0 + c];
  }
  __syncthreads();
#pragma unroll
  for (int q = 0; q < 4; ++q) {
    int h = h0 + rr + q * 8;
    Wt[((size_t)t * DSAE + h) * DIN + d0 + c] = (unsigned short)rne1(s[c][rr + q * 8]);
  }
}

// ---------------- sparse decoder + fused loss --------------------------------
template <bool TRANSPOSED>
__global__ __launch_bounds__(256) void k_decoder(const void* __restrict__ Wd_,
                                                 const float* __restrict__ x,
                                                 const float* __restrict__ bdec,
                                                 const int* __restrict__ sel_idx,
                                                 const float* __restrict__ sel_val,
                                                 float* __restrict__ xhat,
                                                 float* __restrict__ loss) {
  const int r = blockIdx.x, t = r & (T_SZ - 1);
  __shared__ int   si[KSEL];
  __shared__ float sv[KSEL];
  __shared__ float rbuf[4];
  const int tid = threadIdx.x;
  if (tid < KSEL) {
    si[tid] = sel_idx[(size_t)r * KSEL + tid] & (DSAE - 1);  // safety mask
    sv[tid] = sel_val[(size_t)r * KSEL + tid];
  }
  __syncthreads();

  float acc[3];
#pragma unroll
  for (int i = 0; i < 3; ++i) acc[i] = bdec[(size_t)t * DIN + tid + 256 * i];
#pragma unroll 4
  for (int j = 0; j < KSEL; ++j) {
    const int h = si[j];
    const float v = sv[j];
    if (TRANSPOSED) {
      const unsigned short* wrow =
          (const unsigned short*)Wd_ + ((size_t)t * DSAE + h) * DIN;
#pragma unroll
      for (int i = 0; i < 3; ++i)
        acc[i] = fmaf(v, bf16tof(wrow[tid + 256 * i]), acc[i]);
    } else {
      const float* Wd = (const float*)Wd_;
#pragma unroll
      for (int i = 0; i < 3; ++i)
        acc[i] = fmaf(v, Wd[((size_t)t * DIN + tid + 256 * i) * DSAE + h], acc[i]);
    }
  }
  float sq = 0.f;
#pragma unroll
  for (int i = 0; i < 3; ++i) {
    const int d = tid + 256 * i;
    const float xv = x[(size_t)r * DIN + d];
    xhat[(size_t)r * DIN + d] = acc[i];
    const float e = acc[i] - xv;
    sq = fmaf(e, e, sq);
  }
  for (int off = 32; off; off >>= 1) sq += __shfl_down(sq, off);
  if ((tid & 63) == 0) rbuf[tid >> 6] = sq;
  __syncthreads();
  if (tid == 0)
    atomicAdd(loss, (rbuf[0] + rbuf[1] + rbuf[2] + rbuf[3]) * (1.0f / NROWS));
}

// ---------------- host ------------------------------------------------------
extern "C" void kernel_launch(void* const* d_in, const int* in_sizes, int n_in,
                              void* d_out, int out_size, void* d_ws, size_t ws_size,
                              hipStream_t stream) {
  const float* x    = (const float*)d_in[0];
  const float* Wenc = (const float*)d_in[1];
  const float* benc = (const float*)d_in[2];
  const float* Wdec = (const float*)d_in[3];
  const float* bdec = (const float*)d_in[4];
  // d_in[5] is k (==32), baked in as KSEL.

  float* out  = (float*)d_out;
  float* loss = out;
  float* xhat = out + 1;
  float* u    = out + 1 + (size_t)NROWS * DIN;  // (B,T,DSAE) == rows r

  float*          wsf  = (float*)d_ws;
  float*          xc   = wsf + OFF_XC;
  unsigned short* xcp  = (unsigned short*)(wsf + OFF_XCP);
  int*            sidx = (int*)(wsf + OFF_SIDX);
  float*          sval = wsf + OFF_SVAL;
  unsigned short* big  = (unsigned short*)(wsf + OFF_BIG);  // wt (decoder)
  const bool fast = ws_size >= WS_FAST_WORDS * sizeof(float);

  k_zero<<<1, 1, 0, stream>>>(loss);
  k_xc<<<NROWS * DIN / (256 * 8), 256, 0, stream>>>(x, bdec, xc, xcp);  // 768 blocks
  k_encoder<<<dim3(DSAE / 32, T_SZ), 256, 0, stream>>>(xcp, Wenc, benc, u);
  k_select<<<NROWS, 256, 0, stream>>>(xc, Wenc, benc, u, sidx, sval);
  if (fast) {
    k_transpose<<<dim3(DSAE / 32, DIN / 32, T_SZ), 256, 0, stream>>>(Wdec, big);
    k_decoder<true><<<NROWS, 256, 0, stream>>>(big, x, bdec, sidx, sval, xhat, loss);
  } else {
    k_decoder<false><<<NROWS, 256, 0, stream>>>(Wdec, x, bdec, sidx, sval, xhat, loss);
  }
}